// Round 4
// baseline (577.258 us; speedup 1.0000x reference)
//
#include <hip/hip_runtime.h>

// SOM forward: x[128,256] f32, weights[64,64,256] f32
// out (f32, concatenated): bmus[128,2] (256 elems) then diffs[128,64,64,256]
#define BATCH 128
#define SOM_ROWS 64
#define SOM_COLS 64
#define M (SOM_ROWS * SOM_COLS)  // 4096
#define D 256
#define DV (D / 4)               // 64 float4 per row == one wave's lanes

typedef float f32x4 __attribute__((ext_vector_type(4)));

// ---------------------------------------------------------------------------
// Kernel A: single-shot burst writer (fill-kernel imitation).
// vmcnt is a FIFO: any wait for a load forces all earlier-issued stores to
// retire to HBM first. Looped load/store kernels therefore drain the write
// queue every iteration (all three previous versions: ~2.4 TB/s). Here each
// wave issues ALL its loads first (pinned by sched_barrier), then computes,
// then fires 16 back-to-back nt stores and retires — stores are never the
// target of a wait, so the HBM write queues stay full, like the 6.3 TB/s
// fill kernel.
// Wave s (0..32767): b = s>>8 (x frag loop-invariant), 16 consecutive w-rows
// from (s&255)*16; writes one contiguous 16 KB span of diffs.
// ---------------------------------------------------------------------------
__global__ void __launch_bounds__(256) som_diffs(const float* __restrict__ x,
                                                 const float* __restrict__ w,
                                                 float* __restrict__ diffs) {
  const int lane = threadIdx.x & 63;
  const int wib = threadIdx.x >> 6;
  const int s = blockIdx.x * 4 + wib;  // 0..32767
  const int b = s >> 8;                // batch row
  const int mbase = (s & 255) << 4;    // first of 16 consecutive w-rows

  const f32x4* __restrict__ x4 = (const f32x4*)x;
  const f32x4* __restrict__ w4 = (const f32x4*)w;
  f32x4* __restrict__ o4 = (f32x4*)diffs;

  const f32x4* __restrict__ wp = w4 + ((long)mbase << 6) + lane;
  f32x4* __restrict__ op = o4 + ((long)s << 10) + lane;  // span base + lane

  // Phase 1: all loads (L2/L3-resident inputs), nothing else in the FIFO.
  const f32x4 xv = x4[b * DV + lane];
  f32x4 wv[16];
#pragma unroll
  for (int i = 0; i < 16; ++i) wv[i] = wp[i << 6];
  __builtin_amdgcn_sched_barrier(0);  // no store may be hoisted above loads

  // Phase 2: compute + burst stores; no waits on stores before endpgm.
  f32x4 dv[16];
#pragma unroll
  for (int i = 0; i < 16; ++i) dv[i] = xv - wv[i];
#pragma unroll
  for (int i = 0; i < 16; ++i) __builtin_nontemporal_store(dv[i], &op[i << 6]);
}

// ---------------------------------------------------------------------------
// Kernel B: distances + argmin fused, from x,w directly (L2-resident, 4 MB).
// 128 blocks x 1024 threads. Wave wid owns m in [wid*256, wid*256+256),
// 4 rows per step (g = lane>>4 row, c = lane&15 col) -> every load touches
// 16 fully-used cachelines. First-index tie-break matches jnp.argmin.
// Also warms w into every XCD's L2 before kernel A streams it.
// ---------------------------------------------------------------------------
__global__ void __launch_bounds__(1024) som_dist_argmin(
    const float* __restrict__ x, const float* __restrict__ w,
    float* __restrict__ out) {
  __shared__ f32x4 xs[DV];  // x[b], 1 KB
  __shared__ float sval[1024];
  __shared__ int sidx[1024];
  const int b = blockIdx.x;
  const int t = threadIdx.x;
  const int lane = t & 63;
  const int wid = t >> 6;  // 0..15
  const int g = lane >> 4; // 0..3  : row within the 4-row group
  const int c = lane & 15; // 0..15 : float4 index within a 256 B chunk

  const f32x4* __restrict__ x4 = (const f32x4*)x;
  const f32x4* __restrict__ w4 = (const f32x4*)w;

  if (t < DV) xs[t] = x4[b * DV + t];
  __syncthreads();

  float best = 3.4e38f;
  int bidx = 0x7fffffff;

  // 64 steps x 4 rows = 256 m's per wave; m increases monotonically per lane
  // so strict < keeps the earliest index.
  for (int step = 0; step < 64; ++step) {
    const int m = (wid << 8) + (step << 2) + g;
    float s = 0.f;
#pragma unroll
    for (int j = 0; j < 4; ++j) {
      const f32x4 wv = w4[(long)m * DV + (j << 4) + c];
      const f32x4 xv = xs[(j << 4) + c];
      const f32x4 df = xv - wv;
      s += df.x * df.x + df.y * df.y + df.z * df.z + df.w * df.w;
    }
    s += __shfl_xor(s, 1, 64);
    s += __shfl_xor(s, 2, 64);
    s += __shfl_xor(s, 4, 64);
    s += __shfl_xor(s, 8, 64);
    if (s < best) {
      best = s;
      bidx = m;
    }
  }

  sval[t] = best;
  sidx[t] = bidx;
  __syncthreads();
  for (int sr = 512; sr; sr >>= 1) {
    if (t < sr) {
      const float v2 = sval[t + sr];
      const int i2 = sidx[t + sr];
      if (v2 < sval[t] || (v2 == sval[t] && i2 < sidx[t])) {
        sval[t] = v2;
        sidx[t] = i2;
      }
    }
    __syncthreads();
  }
  if (t == 0) {
    out[2 * b] = (float)(sidx[0] >> 6);      // row = m / 64
    out[2 * b + 1] = (float)(sidx[0] & 63);  // col = m % 64
  }
}

extern "C" void kernel_launch(void* const* d_in, const int* in_sizes, int n_in,
                              void* d_out, int out_size, void* d_ws,
                              size_t ws_size, hipStream_t stream) {
  const float* x = (const float*)d_in[0];  // [128,256]
  const float* w = (const float*)d_in[1];  // [64,64,256]
  float* out = (float*)d_out;
  float* bmus = out;                       // first 256 floats
  float* diffs = out + 2 * BATCH;          // then 128*64*64*256

  // Argmin first (also warms w into every XCD's L2), then the burst stream.
  som_dist_argmin<<<BATCH, 1024, 0, stream>>>(x, w, bmus);
  som_diffs<<<8192, 256, 0, stream>>>(x, w, diffs);
}